// Round 12
// baseline (1106.925 us; speedup 1.0000x reference)
//
#include <hip/hip_runtime.h>

namespace {

constexpr int NR = 8192;
constexpr int DD = 512;
constexpr int NSPLIT = 4;
constexpr int KVLEN = NR / NSPLIT;   // 2048
constexpr int KT = 32;               // kv tile
constexpr int NT = KVLEN / KT;       // 64 tiles
constexpr int QB = 32;               // q rows per block (specialized design)
constexpr float SCALE = 0.04419417382415922f;  // 1/sqrt(512)

typedef __bf16 bf16x8 __attribute__((ext_vector_type(8)));
typedef __bf16 bf16x4 __attribute__((ext_vector_type(4)));
typedef float  f32x16 __attribute__((ext_vector_type(16)));
typedef float  f32x4  __attribute__((ext_vector_type(4)));

__device__ __forceinline__ f32x16 mfma32(bf16x8 a, bf16x8 b, f32x16 c) {
    return __builtin_amdgcn_mfma_f32_32x32x16_bf16(a, b, c, 0, 0, 0);
}
__device__ __forceinline__ f32x4 mfma16(bf16x8 a, bf16x8 b, f32x4 c) {
    return __builtin_amdgcn_mfma_f32_16x16x32_bf16(a, b, c, 0, 0, 0);
}

typedef const __attribute__((address_space(1))) void g_void;
typedef __attribute__((address_space(3))) void l_void;
__device__ __forceinline__ void lds_dma16(const void* g, void* l) {
    __builtin_amdgcn_global_load_lds((g_void*)g, (l_void*)l, 16, 0, 0);
}

// K packed as 32KB tile images that ARE the desired (swizzled) LDS layout:
// elem(tile, kv, d) = tile*16384 + kv*512 + ((d>>3) ^ (kv&7))*8 + (d&7)
__device__ __forceinline__ size_t kfa(int n, int d) {
    int tile = n >> 5, kv = n & 31;
    int chunk = (d >> 3) ^ (kv & 7);
    return (size_t)tile * 16384 + kv * 512 + chunk * 8 + (d & 7);
}
// V frag-major: flash PV reads chunk*512 + lane*8 contiguously.
__device__ __forceinline__ size_t vfa(int n, int d) {
    size_t chunk = (size_t)(((n >> 5) * 4 + (d >> 7)) * 8 +
                            ((d >> 6) & 1) * 4 + ((d >> 5) & 1) * 2 + ((n >> 4) & 1));
    return chunk * 512 + ((((n >> 3) & 1) * 32 + (d & 31)) * 8) + (n & 7);
}

// ---------------- fp32 -> bf16 cast ----------------
__global__ void __launch_bounds__(256)
cast_kernel(const float* __restrict__ in, __bf16* __restrict__ out, int n8) {
    int i = blockIdx.x * 256 + threadIdx.x;
    if (i >= n8) return;
    const float4* p = (const float4*)(in + (size_t)i * 8);
    float4 v0 = p[0], v1 = p[1];
    bf16x8 o;
    o[0] = (__bf16)v0.x; o[1] = (__bf16)v0.y; o[2] = (__bf16)v0.z; o[3] = (__bf16)v0.w;
    o[4] = (__bf16)v1.x; o[5] = (__bf16)v1.y; o[6] = (__bf16)v1.z; o[7] = (__bf16)v1.w;
    *(bf16x8*)(out + (size_t)i * 8) = o;
}

// ---------------- adj -> bitmask (u32 per 32 kv) ----------------
__global__ void __launch_bounds__(256)
bitpack_kernel(const int* __restrict__ adj, unsigned* __restrict__ abits) {
    const int w = threadIdx.x >> 6, lane = threadIdx.x & 63;
    const int q = blockIdx.x * 4 + w;
    const int* row = adj + (size_t)q * NR;
    unsigned* orow = abits + (size_t)q * 256;
    for (int i = 0; i < 128; ++i) {
        unsigned long long m = __ballot(row[i * 64 + lane] != 0);
        if (lane == 0) { orow[2 * i] = (unsigned)m; orow[2 * i + 1] = (unsigned)(m >> 32); }
    }
}

// ---------------- GEMM C = A * B^T  (M=8192, N=512, K=512) ----------------
template<bool FINAL>
__global__ void __launch_bounds__(256, 2)
gemm_kernel(const __bf16* __restrict__ A, const __bf16* __restrict__ B0,
            const __bf16* __restrict__ B1, const __bf16* __restrict__ B2,
            __bf16* __restrict__ C0, __bf16* __restrict__ C1, __bf16* __restrict__ C2,
            const float* __restrict__ bias, float* __restrict__ Cf,
            const float* __restrict__ lsum)
{
    const __bf16* B = B0;
    __bf16* Cb = C0;
    int mode = 0;
    if (!FINAL) {
        if (blockIdx.y == 1)      { B = B1; Cb = C1; mode = 1; }
        else if (blockIdx.y == 2) { B = B2; Cb = C2; }
    }
    __shared__ __bf16 As[128][72];
    __shared__ __bf16 Bs[128][72];
    const int t = threadIdx.x;
    const int w = t >> 6, lane = t & 63, lo = lane & 31, hi = lane >> 5;
    const int wm = w >> 1, wn = w & 1;
    const int bm = (blockIdx.x >> 2) * 128;
    const int bn = (blockIdx.x & 3) * 128;

    f32x16 acc[2][2];
    #pragma unroll
    for (int a = 0; a < 2; ++a)
        #pragma unroll
        for (int b = 0; b < 2; ++b)
            #pragma unroll
            for (int r = 0; r < 16; ++r) acc[a][b][r] = 0.f;

    for (int k0 = 0; k0 < DD; k0 += 64) {
        __syncthreads();
        #pragma unroll
        for (int pp = 0; pp < 2; ++pp) {
            int r = pp * 64 + (t >> 2), c = (t & 3) * 16;
            if (FINAL) {
                int row = bm + r;
                float l0 = lsum[row], l1 = lsum[NR + row],
                      l2 = lsum[2 * NR + row], l3 = lsum[3 * NR + row];
                float Winv = 1.f / (l0 + l1 + l2 + l3);
                float w0 = l0 * Winv, w1 = l1 * Winv, w2 = l2 * Winv, w3 = l3 * Winv;
                const size_t stride = (size_t)NR * DD;
                #pragma unroll
                for (int cc = 0; cc < 2; ++cc) {
                    const size_t base = (size_t)row * DD + k0 + c + cc * 8;
                    bf16x8 o0 = *(const bf16x8*)(A + base);
                    bf16x8 o1 = *(const bf16x8*)(A + stride + base);
                    bf16x8 o2 = *(const bf16x8*)(A + 2 * stride + base);
                    bf16x8 o3 = *(const bf16x8*)(A + 3 * stride + base);
                    bf16x8 om;
                    #pragma unroll
                    for (int e = 0; e < 8; ++e)
                        om[e] = (__bf16)(w0 * (float)o0[e] + w1 * (float)o1[e] +
                                         w2 * (float)o2[e] + w3 * (float)o3[e]);
                    *(bf16x8*)&As[r][c + cc * 8] = om;
                }
            } else {
                *(bf16x8*)&As[r][c]     = *(const bf16x8*)(A + (size_t)(bm + r) * DD + k0 + c);
                *(bf16x8*)&As[r][c + 8] = *(const bf16x8*)(A + (size_t)(bm + r) * DD + k0 + c + 8);
            }
            *(bf16x8*)&Bs[r][c]     = *(const bf16x8*)(B + (size_t)(bn + r) * DD + k0 + c);
            *(bf16x8*)&Bs[r][c + 8] = *(const bf16x8*)(B + (size_t)(bn + r) * DD + k0 + c + 8);
        }
        __syncthreads();
        #pragma unroll
        for (int ks = 0; ks < 4; ++ks) {
            bf16x8 a0 = *(const bf16x8*)&As[wm * 64 + lo][ks * 16 + hi * 8];
            bf16x8 a1 = *(const bf16x8*)&As[wm * 64 + 32 + lo][ks * 16 + hi * 8];
            bf16x8 b0 = *(const bf16x8*)&Bs[wn * 64 + lo][ks * 16 + hi * 8];
            bf16x8 b1 = *(const bf16x8*)&Bs[wn * 64 + 32 + lo][ks * 16 + hi * 8];
            acc[0][0] = mfma32(a0, b0, acc[0][0]);
            acc[0][1] = mfma32(a0, b1, acc[0][1]);
            acc[1][0] = mfma32(a1, b0, acc[1][0]);
            acc[1][1] = mfma32(a1, b1, acc[1][1]);
        }
    }
    #pragma unroll
    for (int mi = 0; mi < 2; ++mi)
        #pragma unroll
        for (int ni = 0; ni < 2; ++ni) {
            int col = bn + wn * 64 + ni * 32 + lo;
            float bv = 0.f;
            if (FINAL) bv = bias[col];
            #pragma unroll
            for (int r = 0; r < 16; ++r) {
                int row = bm + wm * 64 + mi * 32 + (r & 3) + 8 * (r >> 2) + 4 * hi;
                if (FINAL) {
                    Cf[(size_t)row * DD + col] = acc[mi][ni][r] + bv;
                } else {
                    size_t a = (mode == 1) ? kfa(row, col) : ((size_t)row * DD + col);
                    Cb[a] = (__bf16)acc[mi][ni][r];
                }
            }
        }
}

// ---------------- repack V row-major -> frag-major (LDS transpose) ----------------
__global__ void __launch_bounds__(256)
repack_v(const __bf16* __restrict__ V, __bf16* __restrict__ VF) {
    __shared__ __bf16 tile[64][72];
    const int t = threadIdx.x;
    const int rb = blockIdx.x * 64;   // n
    const int cb = blockIdx.y * 64;   // d
    #pragma unroll
    for (int pp = 0; pp < 2; ++pp) {
        int r = pp * 32 + (t >> 3), c = (t & 7) * 8;
        *(bf16x8*)&tile[r][c] = *(const bf16x8*)(V + (size_t)(rb + r) * DD + cb + c);
    }
    __syncthreads();
    #pragma unroll
    for (int pp = 0; pp < 2; ++pp) {
        int vid = pp * 256 + t;
        int oct = vid >> 6;
        int dd = vid & 63;
        bf16x8 o;
        #pragma unroll
        for (int e = 0; e < 8; ++e) o[e] = tile[oct * 8 + e][dd];
        *(bf16x8*)(VF + vfa(rb + oct * 8, cb + dd)) = o;
    }
}

// ---------------- flash v5: wave-role specialization ----------------
// grid 1024 (QB=32 x NSPLIT=4, XCD-pinned), 384 threads = 6 waves, 2 blocks/CU,
// __launch_bounds__(384,3) -> 12 waves/CU. Waves 0-1: QK-role (16 q each, mfma16,
// in-register softmax, Pl[b] publish). Waves 2-5: PV-role (128-d slice each, O=64 regs,
// mfma32 from frag-major VF; also DMA-stage K[t+1] from the swizzled KF image).
// One __syncthreads per tile: publishes Pl[b] (QK->PV, dbuf) and K[t+1] (PV DMA -> QK,
// dbuf); the builtin barrier's vmcnt drain is exactly the DMA-completion guarantee.
__global__ void __launch_bounds__(384, 3)
flash_kernel(const __bf16* __restrict__ Qg, const __bf16* __restrict__ KF,
             const __bf16* __restrict__ VF, const unsigned* __restrict__ abits,
             __bf16* __restrict__ Opart, float* __restrict__ lsum_g)
{
    __shared__ __bf16 Klds[2][16384];   // 64 KB K tile double-buffer (swizzled image)
    __shared__ __bf16 Pl[2][QB][44];    // 5.5 KB P double-buffer (44: 2-way-free stride)
    __shared__ float  ll[QB];

    const int t = threadIdx.x;
    const int w = t >> 6, lane = t & 63;
    const int lo = lane & 31, hi = lane >> 5;   // PV indexing
    const int l15 = lane & 15, G = lane >> 4;   // QK indexing
    const int bid = blockIdx.x;
    const int xcd = bid & 7;
    const int split = xcd >> 1;
    const int qblk = (((xcd & 1) << 7) | (bid >> 3)) * QB;
    const int kv0 = split * KVLEN;
    const int tile0 = kv0 >> 5;
    const bool isQK = (w < 2);
    const int pw = w - 2;               // PV wave id 0..3 -> d-slice pw*128

    // QK persistent state
    bf16x8 qa[16];
    const unsigned* abp = nullptr;
    unsigned wcur = 0;
    float l_run = 0.f;
    const int hsw = l15 & 7;
    if (isQK) {
        #pragma unroll
        for (int ks = 0; ks < 16; ++ks)
            qa[ks] = *(const bf16x8*)(Qg + (size_t)(qblk + w * 16 + l15) * DD + ks * 32 + G * 8);
        abp = abits + (size_t)(qblk + w * 16 + l15) * 256 + tile0;
        wcur = abp[0];
    }

    // PV persistent state: O[j] = 32q x 32d sub-tile at d = pw*128 + j*32
    f32x16 O[4];
    #pragma unroll
    for (int j = 0; j < 4; ++j)
        #pragma unroll
        for (int r = 0; r < 16; ++r) O[j][r] = 0.f;

    // ---- prologue: PV waves stage K[0] into buf0 ----
    if (!isQK) {
        #pragma unroll
        for (int i = 0; i < 8; ++i)
            lds_dma16(KF + (size_t)tile0 * 16384 + pw * 4096 + i * 512 + lane * 8,
                      &Klds[0][pw * 4096 + i * 512]);
    }
    __syncthreads();

    for (int tl = 0; tl < NT; ++tl) {
        const int b = tl & 1;
        const int tn = (tl + 1 == NT) ? 0 : tl + 1;   // wrap keeps DMA count uniform
        if (isQK) {
            unsigned wn = abp[tn];   // prefetch early; consumed after barrier
            f32x4 St0, St1;
            #pragma unroll
            for (int r = 0; r < 4; ++r) { St0[r] = 0.f; St1[r] = 0.f; }
            __builtin_amdgcn_s_setprio(1);
            #pragma unroll
            for (int ks = 0; ks < 16; ++ks) {
                int csw = (((ks * 4 + G) ^ hsw) << 3);
                bf16x8 k0 = *(const bf16x8*)&Klds[b][l15 * 512 + csw];
                bf16x8 k1 = *(const bf16x8*)&Klds[b][(16 + l15) * 512 + csw];
                St0 = mfma16(k0, qa[ks], St0);
                St1 = mfma16(k1, qa[ks], St1);
            }
            __builtin_amdgcn_s_setprio(0);
            float l_add = 0.f;
            bf16x4 p0v, p1v;
            #pragma unroll
            for (int r = 0; r < 4; ++r) {
                float pv0 = ((wcur >> (G * 4 + r)) & 1u) ? __expf(St0[r] * SCALE) : 0.f;
                float pv1 = ((wcur >> (16 + G * 4 + r)) & 1u) ? __expf(St1[r] * SCALE) : 0.f;
                l_add += pv0 + pv1;
                p0v[r] = (__bf16)pv0; p1v[r] = (__bf16)pv1;
            }
            *(bf16x4*)&Pl[b][w * 16 + l15][G * 4]      = p0v;
            *(bf16x4*)&Pl[b][w * 16 + l15][16 + G * 4] = p1v;
            float a = l_add + __shfl_xor(l_add, 16);
            a += __shfl_xor(a, 32);
            l_run += a;
            wcur = wn;
        } else {
            // stage K[tn] into the buffer QK is NOT reading this tile
            #pragma unroll
            for (int i = 0; i < 8; ++i)
                lds_dma16(KF + (size_t)(tile0 + tn) * 16384 + pw * 4096 + i * 512 + lane * 8,
                          &Klds[b ^ 1][pw * 4096 + i * 512]);
            if (tl > 0) {
                // PV(tl-1): P from Pl[b^1] (published at last barrier), V from L2
                bf16x8 pa0 = *(const bf16x8*)&Pl[b ^ 1][lo][hi * 8];
                bf16x8 pa1 = *(const bf16x8*)&Pl[b ^ 1][lo][16 + hi * 8];
                const __bf16* vf = VF + (size_t)((tile0 + tl - 1) * 4 + pw) * 4096;
                __builtin_amdgcn_s_setprio(1);
                #pragma unroll
                for (int jh = 0; jh < 2; ++jh) {   // two halves: bounded vb liveness
                    bf16x8 vb0 = *(const bf16x8*)(vf + (jh * 4 + 0) * 512 + lane * 8);
                    bf16x8 vb1 = *(const bf16x8*)(vf + (jh * 4 + 1) * 512 + lane * 8);
                    bf16x8 vb2 = *(const bf16x8*)(vf + (jh * 4 + 2) * 512 + lane * 8);
                    bf16x8 vb3 = *(const bf16x8*)(vf + (jh * 4 + 3) * 512 + lane * 8);
                    O[jh * 2 + 0] = mfma32(pa0, vb0, O[jh * 2 + 0]);
                    O[jh * 2 + 0] = mfma32(pa1, vb1, O[jh * 2 + 0]);
                    O[jh * 2 + 1] = mfma32(pa0, vb2, O[jh * 2 + 1]);
                    O[jh * 2 + 1] = mfma32(pa1, vb3, O[jh * 2 + 1]);
                }
                __builtin_amdgcn_s_setprio(0);
            }
        }
        __syncthreads();   // publishes Pl[b] + K[tn]; drains PV's DMAs
    }
    // ---- epilogue: QK publishes l; PV finishes PV(NT-1) ----
    if (isQK) {
        if (lane < 16) {
            ll[w * 16 + lane] = l_run;
            lsum_g[(size_t)split * NR + qblk + w * 16 + lane] = l_run;
        }
    } else {
        const int pb = (NT - 1) & 1;
        bf16x8 pa0 = *(const bf16x8*)&Pl[pb][lo][hi * 8];
        bf16x8 pa1 = *(const bf16x8*)&Pl[pb][lo][16 + hi * 8];
        const __bf16* vf = VF + (size_t)((tile0 + NT - 1) * 4 + pw) * 4096;
        #pragma unroll
        for (int j = 0; j < 4; ++j) {
            bf16x8 vb0 = *(const bf16x8*)(vf + (j * 2 + 0) * 512 + lane * 8);
            bf16x8 vb1 = *(const bf16x8*)(vf + (j * 2 + 1) * 512 + lane * 8);
            O[j] = mfma32(pa0, vb0, O[j]);
            O[j] = mfma32(pa1, vb1, O[j]);
        }
    }
    __syncthreads();
    if (!isQK) {
        #pragma unroll
        for (int g = 0; g < 4; ++g) {
            float4 lv = *(const float4*)&ll[g * 8 + 4 * hi];
            #pragma unroll
            for (int e = 0; e < 4; ++e) {
                float lval = (&lv.x)[e];
                float inv = (lval > 0.f) ? 1.f / lval : 0.f;
                int row = qblk + g * 8 + 4 * hi + e;
                #pragma unroll
                for (int j = 0; j < 4; ++j) {
                    int col = pw * 128 + j * 32 + lo;
                    Opart[(size_t)split * NR * DD + (size_t)row * DD + col] =
                        (__bf16)(O[j][g * 4 + e] * inv);
                }
            }
        }
    }
}

} // namespace

extern "C" void kernel_launch(void* const* d_in, const int* in_sizes, int n_in,
                              void* d_out, int out_size, void* d_ws, size_t ws_size,
                              hipStream_t stream)
{
    (void)in_sizes; (void)n_in; (void)out_size; (void)ws_size;
    const float* X  = (const float*)d_in[0];
    const int*   adj = (const int*)d_in[1];
    const float* Wq = (const float*)d_in[2];
    const float* Wk = (const float*)d_in[3];
    const float* Wv = (const float*)d_in[4];
    const float* Wo = (const float*)d_in[5];
    const float* bo = (const float*)d_in[6];
    float* out = (float*)d_out;

    char* ws = (char*)d_ws;
    __bf16* Xb   = (__bf16*)(ws + 0);          // 8.39 MB
    __bf16* Wqb  = (__bf16*)(ws + 8388608);
    __bf16* Wkb  = (__bf16*)(ws + 8912896);
    __bf16* Wvb  = (__bf16*)(ws + 9437184);
    __bf16* Wob  = (__bf16*)(ws + 9961472);
    __bf16* Qb   = (__bf16*)(ws + 10485760);   // 8192x512 row-major
    __bf16* KFb  = (__bf16*)(ws + 18874368);   // swizzled K tile images (8.39 MB)
    __bf16* VFb  = (__bf16*)(ws + 27262976);   // frag-major V (8.39 MB)
    unsigned* abits = (unsigned*)(ws + 35651584);  // 8192x256 u32 (8.39 MB)
    __bf16* Vb   = (__bf16*)(ws + 44040192);   // row-major V (dead after repack; inside Op)
    __bf16* Op   = (__bf16*)(ws + 44040192);   // 4x8192x512 bf16 (33.55 MB)
    float*  lseb = (float*)(ws + 77594624);    // 4x8192 f32

    bitpack_kernel<<<2048, 256, 0, stream>>>(adj, abits);
    cast_kernel<<<2048, 256, 0, stream>>>(X,  Xb,  NR * DD / 8);
    cast_kernel<<<128,  256, 0, stream>>>(Wq, Wqb, DD * DD / 8);
    cast_kernel<<<128,  256, 0, stream>>>(Wk, Wkb, DD * DD / 8);
    cast_kernel<<<128,  256, 0, stream>>>(Wv, Wvb, DD * DD / 8);
    cast_kernel<<<128,  256, 0, stream>>>(Wo, Wob, DD * DD / 8);

    gemm_kernel<false><<<dim3(256, 3), 256, 0, stream>>>(Xb, Wqb, Wkb, Wvb,
                                                         Qb, KFb, Vb, nullptr, nullptr, nullptr);
    repack_v<<<dim3(128, 8), 256, 0, stream>>>(Vb, VFb);
    flash_kernel<<<1024, 384, 0, stream>>>(Qb, KFb, VFb, abits, Op, lseb);
    gemm_kernel<true><<<dim3(256, 1), 256, 0, stream>>>(Op, Wob, nullptr, nullptr,
                                                        nullptr, nullptr, nullptr, bo, out, lseb);
}

// Round 13
// 430.715 us; speedup vs baseline: 2.5700x; 2.5700x over previous
//
#include <hip/hip_runtime.h>

namespace {

constexpr int NR = 8192;
constexpr int DD = 512;
constexpr int NSPLIT = 4;
constexpr int KVLEN = NR / NSPLIT;   // 2048
constexpr int KT = 32;               // kv tile
constexpr int NT = KVLEN / KT;       // 64 tiles
constexpr int QB = 64;               // q rows per block
constexpr float SCALE = 0.04419417382415922f;  // 1/sqrt(512)

typedef __bf16 bf16x8 __attribute__((ext_vector_type(8)));
typedef __bf16 bf16x4 __attribute__((ext_vector_type(4)));
typedef float  f32x16 __attribute__((ext_vector_type(16)));
typedef float  f32x4  __attribute__((ext_vector_type(4)));

__device__ __forceinline__ f32x16 mfma32(bf16x8 a, bf16x8 b, f32x16 c) {
    return __builtin_amdgcn_mfma_f32_32x32x16_bf16(a, b, c, 0, 0, 0);
}
__device__ __forceinline__ f32x4 mfma16(bf16x8 a, bf16x8 b, f32x4 c) {
    return __builtin_amdgcn_mfma_f32_16x16x32_bf16(a, b, c, 0, 0, 0);
}

typedef const __attribute__((address_space(1))) void g_void;
typedef __attribute__((address_space(3))) void l_void;
__device__ __forceinline__ void lds_dma16(const void* g, void* l) {
    __builtin_amdgcn_global_load_lds((g_void*)g, (l_void*)l, 16, 0, 0);
}

__device__ __forceinline__ bf16x8 cvt8(float4 a, float4 b) {
    bf16x8 o;
    o[0] = (__bf16)a.x; o[1] = (__bf16)a.y; o[2] = (__bf16)a.z; o[3] = (__bf16)a.w;
    o[4] = (__bf16)b.x; o[5] = (__bf16)b.y; o[6] = (__bf16)b.z; o[7] = (__bf16)b.w;
    return o;
}

// K packed as 32KB tile images that ARE the desired (swizzled) LDS layout:
// elem(tile, kv, d) = tile*16384 + kv*512 + ((d>>3) ^ (kv&7))*8 + (d&7)
__device__ __forceinline__ size_t kfa(int n, int d) {
    int tile = n >> 5, kv = n & 31;
    int chunk = (d >> 3) ^ (kv & 7);
    return (size_t)tile * 16384 + kv * 512 + chunk * 8 + (d & 7);
}
// V frag-major: flash PV reads chunk*512 + lane*8 contiguously.
__device__ __forceinline__ size_t vfa(int n, int d) {
    size_t chunk = (size_t)(((n >> 5) * 4 + (d >> 7)) * 8 +
                            ((d >> 6) & 1) * 4 + ((d >> 5) & 1) * 2 + ((n >> 4) & 1));
    return chunk * 512 + ((((n >> 3) & 1) * 32 + (d & 31)) * 8) + (n & 7);
}

// ---------------- adj -> bitmask (u32 per 32 kv) ----------------
__global__ void __launch_bounds__(256)
bitpack_kernel(const int* __restrict__ adj, unsigned* __restrict__ abits) {
    const int w = threadIdx.x >> 6, lane = threadIdx.x & 63;
    const int q = blockIdx.x * 4 + w;
    const int* row = adj + (size_t)q * NR;
    unsigned* orow = abits + (size_t)q * 256;
    for (int i = 0; i < 128; ++i) {
        unsigned long long m = __ballot(row[i * 64 + lane] != 0);
        if (lane == 0) { orow[2 * i] = (unsigned)m; orow[2 * i + 1] = (unsigned)(m >> 32); }
    }
}

// ---------------- GEMM C = A * B^T  (M=8192, N=512, K=512), fused fp32->bf16 staging --------
// FINAL=false: A = X (fp32); y=0 -> Q row-major; y=1 -> K swizzled-tile-image; y=2 -> V row-major.
// FINAL=true : A = Opart (bf16, 4 split panels, lsum-weighted merge in staging); B = Wo fp32;
//              +bias; fp32 out.
template<bool FINAL>
__global__ void __launch_bounds__(256, 2)
gemm_kernel(const float* __restrict__ Xf, const __bf16* __restrict__ Aop,
            const float* __restrict__ B0, const float* __restrict__ B1,
            const float* __restrict__ B2,
            __bf16* __restrict__ C0, __bf16* __restrict__ C1, __bf16* __restrict__ C2,
            const float* __restrict__ bias, float* __restrict__ Cf,
            const float* __restrict__ lsum)
{
    const float* B = B0;
    __bf16* Cb = C0;
    int mode = 0;
    if (!FINAL) {
        if (blockIdx.y == 1)      { B = B1; Cb = C1; mode = 1; }
        else if (blockIdx.y == 2) { B = B2; Cb = C2; }
    }
    __shared__ __bf16 As[128][72];
    __shared__ __bf16 Bs[128][72];
    const int t = threadIdx.x;
    const int w = t >> 6, lane = t & 63, lo = lane & 31, hi = lane >> 5;
    const int wm = w >> 1, wn = w & 1;
    const int bm = (blockIdx.x >> 2) * 128;
    const int bn = (blockIdx.x & 3) * 128;

    f32x16 acc[2][2];
    #pragma unroll
    for (int a = 0; a < 2; ++a)
        #pragma unroll
        for (int b = 0; b < 2; ++b)
            #pragma unroll
            for (int r = 0; r < 16; ++r) acc[a][b][r] = 0.f;

    for (int k0 = 0; k0 < DD; k0 += 64) {
        __syncthreads();
        #pragma unroll
        for (int pp = 0; pp < 2; ++pp) {
            int r = pp * 64 + (t >> 2), c = (t & 3) * 16;
            if (FINAL) {
                // fused merge: As = sum_i w_i * Opart[i]
                int row = bm + r;
                float l0 = lsum[row], l1 = lsum[NR + row],
                      l2 = lsum[2 * NR + row], l3 = lsum[3 * NR + row];
                float Winv = 1.f / (l0 + l1 + l2 + l3);
                float w0 = l0 * Winv, w1 = l1 * Winv, w2 = l2 * Winv, w3 = l3 * Winv;
                const size_t stride = (size_t)NR * DD;
                #pragma unroll
                for (int cc = 0; cc < 2; ++cc) {
                    const size_t base = (size_t)row * DD + k0 + c + cc * 8;
                    bf16x8 o0 = *(const bf16x8*)(Aop + base);
                    bf16x8 o1 = *(const bf16x8*)(Aop + stride + base);
                    bf16x8 o2 = *(const bf16x8*)(Aop + 2 * stride + base);
                    bf16x8 o3 = *(const bf16x8*)(Aop + 3 * stride + base);
                    bf16x8 om;
                    #pragma unroll
                    for (int e = 0; e < 8; ++e)
                        om[e] = (__bf16)(w0 * (float)o0[e] + w1 * (float)o1[e] +
                                         w2 * (float)o2[e] + w3 * (float)o3[e]);
                    *(bf16x8*)&As[r][c + cc * 8] = om;
                }
            } else {
                const float* asrc = Xf + (size_t)(bm + r) * DD + k0 + c;
                float4 a0 = *(const float4*)(asrc);
                float4 a1 = *(const float4*)(asrc + 4);
                float4 a2 = *(const float4*)(asrc + 8);
                float4 a3 = *(const float4*)(asrc + 12);
                *(bf16x8*)&As[r][c]     = cvt8(a0, a1);
                *(bf16x8*)&As[r][c + 8] = cvt8(a2, a3);
            }
            const float* bsrc = B + (size_t)(bn + r) * DD + k0 + c;
            float4 b0 = *(const float4*)(bsrc);
            float4 b1 = *(const float4*)(bsrc + 4);
            float4 b2 = *(const float4*)(bsrc + 8);
            float4 b3 = *(const float4*)(bsrc + 12);
            *(bf16x8*)&Bs[r][c]     = cvt8(b0, b1);
            *(bf16x8*)&Bs[r][c + 8] = cvt8(b2, b3);
        }
        __syncthreads();
        #pragma unroll
        for (int ks = 0; ks < 4; ++ks) {
            bf16x8 a0 = *(const bf16x8*)&As[wm * 64 + lo][ks * 16 + hi * 8];
            bf16x8 a1 = *(const bf16x8*)&As[wm * 64 + 32 + lo][ks * 16 + hi * 8];
            bf16x8 b0 = *(const bf16x8*)&Bs[wn * 64 + lo][ks * 16 + hi * 8];
            bf16x8 b1 = *(const bf16x8*)&Bs[wn * 64 + 32 + lo][ks * 16 + hi * 8];
            acc[0][0] = mfma32(a0, b0, acc[0][0]);
            acc[0][1] = mfma32(a0, b1, acc[0][1]);
            acc[1][0] = mfma32(a1, b0, acc[1][0]);
            acc[1][1] = mfma32(a1, b1, acc[1][1]);
        }
    }
    #pragma unroll
    for (int mi = 0; mi < 2; ++mi)
        #pragma unroll
        for (int ni = 0; ni < 2; ++ni) {
            int col = bn + wn * 64 + ni * 32 + lo;
            float bv = 0.f;
            if (FINAL) bv = bias[col];
            #pragma unroll
            for (int r = 0; r < 16; ++r) {
                int row = bm + wm * 64 + mi * 32 + (r & 3) + 8 * (r >> 2) + 4 * hi;
                if (FINAL) {
                    Cf[(size_t)row * DD + col] = acc[mi][ni][r] + bv;
                } else {
                    size_t a = (mode == 1) ? kfa(row, col) : ((size_t)row * DD + col);
                    Cb[a] = (__bf16)acc[mi][ni][r];
                }
            }
        }
}

// ---------------- repack V row-major -> frag-major (LDS transpose) ----------------
__global__ void __launch_bounds__(256)
repack_v(const __bf16* __restrict__ V, __bf16* __restrict__ VF) {
    __shared__ __bf16 tile[64][72];
    const int t = threadIdx.x;
    const int rb = blockIdx.x * 64;   // n
    const int cb = blockIdx.y * 64;   // d
    #pragma unroll
    for (int pp = 0; pp < 2; ++pp) {
        int r = pp * 32 + (t >> 3), c = (t & 7) * 8;
        *(bf16x8*)&tile[r][c] = *(const bf16x8*)(V + (size_t)(rb + r) * DD + cb + c);
    }
    __syncthreads();
    #pragma unroll
    for (int pp = 0; pp < 2; ++pp) {
        int vid = pp * 256 + t;
        int oct = vid >> 6;
        int dd = vid & 63;
        bf16x8 o;
        #pragma unroll
        for (int e = 0; e < 8; ++e) o[e] = tile[oct * 8 + e][dd];
        *(bf16x8*)(VF + vfa(rb + oct * 8, cb + dd)) = o;
    }
}

// ---------------- flash v4 (r11 verbatim): single merged compute region per tile ----------------
__global__ void __launch_bounds__(256, 2)
flash_kernel(const __bf16* __restrict__ Qg, const __bf16* __restrict__ KF,
             const __bf16* __restrict__ VF, const unsigned* __restrict__ abits,
             __bf16* __restrict__ Opart, float* __restrict__ lsum_g)
{
    __shared__ __bf16 Klds[2][16384];   // 64 KB K tile double-buffer (swizzled image)
    __shared__ __bf16 Pl[2][QB][40];    // P double-buffer
    __shared__ float  ll[QB];

    const int t = threadIdx.x;
    const int w = t >> 6, lane = t & 63;
    const int lo = lane & 31, hi = lane >> 5;   // PV indexing (32-wide)
    const int l15 = lane & 15, G = lane >> 4;   // QK indexing (16-wide)
    const int bid = blockIdx.x;
    const int xcd = bid & 7;
    const int split = xcd >> 1;
    const int qblk = (((xcd & 1) << 6) | (bid >> 3)) * QB;
    const int kv0 = split * KVLEN;
    const int tile0 = kv0 >> 5;

    // Q B-frags: q = qblk + w*16 + l15 ; k(d) = ks*32 + G*8 + e
    bf16x8 qa[16];
    #pragma unroll
    for (int ks = 0; ks < 16; ++ks)
        qa[ks] = *(const bf16x8*)(Qg + (size_t)(qblk + w * 16 + l15) * DD + ks * 32 + G * 8);

    f32x16 O[2][2][2];  // [h][mi][ni]
    #pragma unroll
    for (int h = 0; h < 2; ++h)
        #pragma unroll
        for (int a = 0; a < 2; ++a)
            #pragma unroll
            for (int b = 0; b < 2; ++b)
                #pragma unroll
                for (int r = 0; r < 16; ++r) O[h][a][b][r] = 0.f;

    const unsigned* abp = abits + (size_t)(qblk + w * 16 + l15) * 256 + tile0;
    unsigned wcur = abp[0];
    float l_run = 0.f;
    const int hsw = l15 & 7;     // K swizzle key

    // ---- prologue: stage K[0] into buf0, wait, barrier ----
    #pragma unroll
    for (int i = 0; i < 8; ++i)
        lds_dma16(KF + (size_t)tile0 * 16384 + w * 4096 + i * 512 + lane * 8,
                  &Klds[0][w * 4096 + i * 512]);
    asm volatile("s_waitcnt vmcnt(0)" ::: "memory");
    __syncthreads();

    // ---- peeled tile 0: DMA K1; QK(0); softmax(0); barrier ----
    {
        #pragma unroll
        for (int i = 0; i < 8; ++i)
            lds_dma16(KF + (size_t)(tile0 + 1) * 16384 + w * 4096 + i * 512 + lane * 8,
                      &Klds[1][w * 4096 + i * 512]);
        f32x4 St0, St1;
        #pragma unroll
        for (int r = 0; r < 4; ++r) { St0[r] = 0.f; St1[r] = 0.f; }
        #pragma unroll
        for (int ks = 0; ks < 16; ++ks) {
            int csw = (((ks * 4 + G) ^ hsw) << 3);
            bf16x8 k0 = *(const bf16x8*)&Klds[0][l15 * 512 + csw];
            bf16x8 k1 = *(const bf16x8*)&Klds[0][(16 + l15) * 512 + csw];
            St0 = mfma16(k0, qa[ks], St0);
            St1 = mfma16(k1, qa[ks], St1);
        }
        float l_add = 0.f;
        bf16x4 p0v, p1v;
        #pragma unroll
        for (int r = 0; r < 4; ++r) {
            float pv0 = ((wcur >> (G * 4 + r)) & 1u) ? __expf(St0[r] * SCALE) : 0.f;
            float pv1 = ((wcur >> (16 + G * 4 + r)) & 1u) ? __expf(St1[r] * SCALE) : 0.f;
            l_add += pv0 + pv1;
            p0v[r] = (__bf16)pv0; p1v[r] = (__bf16)pv1;
        }
        *(bf16x4*)&Pl[0][w * 16 + l15][G * 4]      = p0v;
        *(bf16x4*)&Pl[0][w * 16 + l15][16 + G * 4] = p1v;
        float a = l_add + __shfl_xor(l_add, 16);
        a += __shfl_xor(a, 32);
        l_run += a;
        unsigned wnxt = abp[1];
        asm volatile("s_waitcnt vmcnt(1) lgkmcnt(0)" ::: "memory");
        asm volatile("s_barrier" ::: "memory");
        wcur = wnxt;
    }

    for (int tl = 1; tl < NT; ++tl) {
        const int b = tl & 1;
        const int tn = (tl + 1 == NT) ? 0 : tl + 1;

        // ---- oldest vmem: V(tl-1) loads (8) so their waits never drain the DMAs ----
        const __bf16* vf = VF + (size_t)((tile0 + tl - 1) * 4 + w) * 4096;
        bf16x8 vb[8];
        #pragma unroll
        for (int i = 0; i < 8; ++i)
            vb[i] = *(const bf16x8*)(vf + i * 512 + lane * 8);
        // ---- pa reads (LDS, ready since last barrier) ----
        bf16x8 pa[2][2];
        #pragma unroll
        for (int mi = 0; mi < 2; ++mi)
            #pragma unroll
            for (int ksp = 0; ksp < 2; ++ksp)
                pa[mi][ksp] = *(const bf16x8*)&Pl[b ^ 1][mi * 32 + lo][ksp * 16 + hi * 8];
        // ---- issue K(tn) staging into buf[b^1] ----
        #pragma unroll
        for (int i = 0; i < 8; ++i)
            lds_dma16(KF + (size_t)(tile0 + tn) * 16384 + w * 4096 + i * 512 + lane * 8,
                      &Klds[b ^ 1][w * 4096 + i * 512]);

        __builtin_amdgcn_s_setprio(1);
        // ---- merged region: QK(tl) + PV(tl-1), two independent MFMA streams ----
        f32x4 St0, St1;
        #pragma unroll
        for (int r = 0; r < 4; ++r) { St0[r] = 0.f; St1[r] = 0.f; }
        #pragma unroll
        for (int ks = 0; ks < 16; ++ks) {
            int csw = (((ks * 4 + G) ^ hsw) << 3);
            bf16x8 k0 = *(const bf16x8*)&Klds[b][l15 * 512 + csw];
            bf16x8 k1 = *(const bf16x8*)&Klds[b][(16 + l15) * 512 + csw];
            St0 = mfma16(k0, qa[ks], St0);
            St1 = mfma16(k1, qa[ks], St1);
        }
        #pragma unroll
        for (int h = 0; h < 2; ++h)
            #pragma unroll
            for (int ni = 0; ni < 2; ++ni) {
                O[h][0][ni] = mfma32(pa[0][0], vb[h * 4 + ni * 2 + 0], O[h][0][ni]);
                O[h][1][ni] = mfma32(pa[1][0], vb[h * 4 + ni * 2 + 0], O[h][1][ni]);
                O[h][0][ni] = mfma32(pa[0][1], vb[h * 4 + ni * 2 + 1], O[h][0][ni]);
                O[h][1][ni] = mfma32(pa[1][1], vb[h * 4 + ni * 2 + 1], O[h][1][ni]);
            }
        __builtin_amdgcn_s_setprio(0);

        // ---- softmax(tl) in-register ----
        {
            float l_add = 0.f;
            bf16x4 p0v, p1v;
            #pragma unroll
            for (int r = 0; r < 4; ++r) {
                float pv0 = ((wcur >> (G * 4 + r)) & 1u) ? __expf(St0[r] * SCALE) : 0.f;
                float pv1 = ((wcur >> (16 + G * 4 + r)) & 1u) ? __expf(St1[r] * SCALE) : 0.f;
                l_add += pv0 + pv1;
                p0v[r] = (__bf16)pv0; p1v[r] = (__bf16)pv1;
            }
            *(bf16x4*)&Pl[b][w * 16 + l15][G * 4]      = p0v;
            *(bf16x4*)&Pl[b][w * 16 + l15][16 + G * 4] = p1v;
            float a = l_add + __shfl_xor(l_add, 16);
            a += __shfl_xor(a, 32);
            l_run += a;
        }
        unsigned wnxt = abp[tn];
        // retire V loads + K DMAs (older); wnxt (newest) may stay in flight.
        asm volatile("s_waitcnt vmcnt(1) lgkmcnt(0)" ::: "memory");
        asm volatile("s_barrier" ::: "memory");
        wcur = wnxt;
    }
    // ---- epilogue PV(NT-1) ----
    {
        const int b = (NT - 1) & 1;
        bf16x8 pa[2][2];
        #pragma unroll
        for (int mi = 0; mi < 2; ++mi)
            #pragma unroll
            for (int ksp = 0; ksp < 2; ++ksp)
                pa[mi][ksp] = *(const bf16x8*)&Pl[b][mi * 32 + lo][ksp * 16 + hi * 8];
        const __bf16* vf = VF + (size_t)((tile0 + NT - 1) * 4 + w) * 4096;
        #pragma unroll
        for (int h = 0; h < 2; ++h)
            #pragma unroll
            for (int ni = 0; ni < 2; ++ni) {
                bf16x8 vb0 = *(const bf16x8*)(vf + (h * 4 + ni * 2 + 0) * 512 + lane * 8);
                bf16x8 vb1 = *(const bf16x8*)(vf + (h * 4 + ni * 2 + 1) * 512 + lane * 8);
                O[h][0][ni] = mfma32(pa[0][0], vb0, O[h][0][ni]);
                O[h][1][ni] = mfma32(pa[1][0], vb0, O[h][1][ni]);
                O[h][0][ni] = mfma32(pa[0][1], vb1, O[h][0][ni]);
                O[h][1][ni] = mfma32(pa[1][1], vb1, O[h][1][ni]);
            }
    }
    // ---- publish l, normalize, store Opart ----
    if (lane < 16) {
        ll[w * 16 + lane] = l_run;
        lsum_g[(size_t)split * NR + qblk + w * 16 + lane] = l_run;
    }
    __syncthreads();
    #pragma unroll
    for (int mi = 0; mi < 2; ++mi)
        #pragma unroll
        for (int g = 0; g < 4; ++g) {
            float4 lv = *(const float4*)&ll[mi * 32 + 8 * g + 4 * hi];
            #pragma unroll
            for (int j = 0; j < 4; ++j) {
                float lval = (&lv.x)[j];
                float inv = (lval > 0.f) ? 1.f / lval : 0.f;
                int row = qblk + mi * 32 + 8 * g + 4 * hi + j;
                #pragma unroll
                for (int h = 0; h < 2; ++h)
                    #pragma unroll
                    for (int ni = 0; ni < 2; ++ni) {
                        int col = w * 128 + h * 64 + ni * 32 + lo;
                        Opart[(size_t)split * NR * DD + (size_t)row * DD + col] =
                            (__bf16)(O[h][mi][ni][g * 4 + j] * inv);
                    }
            }
        }
}

} // namespace

extern "C" void kernel_launch(void* const* d_in, const int* in_sizes, int n_in,
                              void* d_out, int out_size, void* d_ws, size_t ws_size,
                              hipStream_t stream)
{
    (void)in_sizes; (void)n_in; (void)out_size; (void)ws_size;
    const float* X  = (const float*)d_in[0];
    const int*   adj = (const int*)d_in[1];
    const float* Wq = (const float*)d_in[2];
    const float* Wk = (const float*)d_in[3];
    const float* Wv = (const float*)d_in[4];
    const float* Wo = (const float*)d_in[5];
    const float* bo = (const float*)d_in[6];
    float* out = (float*)d_out;

    char* ws = (char*)d_ws;
    __bf16* Qb   = (__bf16*)(ws + 0);          // 8192x512 row-major (8.39 MB)
    __bf16* KFb  = (__bf16*)(ws + 8388608);    // swizzled K tile images (8.39 MB)
    __bf16* VFb  = (__bf16*)(ws + 16777216);   // frag-major V (8.39 MB)
    unsigned* abits = (unsigned*)(ws + 25165824);  // 8192x256 u32 (8.39 MB)
    __bf16* Vb   = (__bf16*)(ws + 33554432);   // row-major V (dead after repack; inside Op)
    __bf16* Op   = (__bf16*)(ws + 33554432);   // 4x8192x512 bf16 (33.55 MB)
    float*  lseb = (float*)(ws + 67108864);    // 4x8192 f32
    // total = 67,239,936 bytes

    bitpack_kernel<<<2048, 256, 0, stream>>>(adj, abits);
    gemm_kernel<false><<<dim3(256, 3), 256, 0, stream>>>(X, nullptr, Wq, Wk, Wv,
                                                         Qb, KFb, Vb,
                                                         nullptr, nullptr, nullptr);
    repack_v<<<dim3(128, 8), 256, 0, stream>>>(Vb, VFb);
    flash_kernel<<<512, 256, 0, stream>>>(Qb, KFb, VFb, abits, Op, lseb);
    gemm_kernel<true><<<dim3(256, 1), 256, 0, stream>>>(nullptr, Op, Wo, nullptr, nullptr,
                                                        nullptr, nullptr, nullptr,
                                                        bo, out, lseb);
}